// Round 2
// baseline (41014.966 us; speedup 1.0000x reference)
//
#include <hip/hip_runtime.h>
#include <cstdint>
#include <cmath>

#define S_LEN 1024
#define BATCH 64
#define IN_SZ 256
#define HID 512
#define OUT_SZ 256
#define WIH_LD 768  // W_ih leading dim = IN_SZ + HID
#define BH (BATCH * HID)            // 32768
#define XP_FLOATS (S_LEN * BH)      // 33,554,432 floats (128 MB)

// ws layout (floats):
//  [0, XP_FLOATS)                      xp / hidden_seq  [s][b][h]
//  [XP_FLOATS, XP_FLOATS+2*BH)         hbuf: double-buffered h state [parity][b][h]
//  [XP_FLOATS+2*BH, +BATCH uints)      cnt: per-batch monotonic step counter

// xp[s][b][h] = dot(x[b][s][:], W_ih[h][0:256]) + b_ih[h]
__global__ __launch_bounds__(256) void xproj(const float* __restrict__ x,
                                             const float* __restrict__ W_ih,
                                             const float* __restrict__ b_ih,
                                             float* __restrict__ xp) {
    __shared__ float As[16][64];   // As[k][b]
    __shared__ float Bs[16][64];   // Bs[k][h]
    const int s   = blockIdx.x;
    const int nb  = blockIdx.y * 64;
    const int tid = threadIdx.x;
    const int lm  = tid >> 2;          // 0..63
    const int lk  = (tid & 3) << 2;    // 0,4,8,12
    const int mr  = (tid & 15) << 2;   // b sub-tile
    const int nr  = (tid >> 4) << 2;   // h sub-tile
    float acc[4][4] = {};
    for (int k0 = 0; k0 < IN_SZ; k0 += 16) {
        float4 av = *(const float4*)(x + ((size_t)lm * S_LEN + s) * IN_SZ + k0 + lk);
        float4 bv = *(const float4*)(W_ih + (size_t)(nb + lm) * WIH_LD + k0 + lk);
        __syncthreads();
        As[lk + 0][lm] = av.x; As[lk + 1][lm] = av.y;
        As[lk + 2][lm] = av.z; As[lk + 3][lm] = av.w;
        Bs[lk + 0][lm] = bv.x; Bs[lk + 1][lm] = bv.y;
        Bs[lk + 2][lm] = bv.z; Bs[lk + 3][lm] = bv.w;
        __syncthreads();
#pragma unroll
        for (int kk = 0; kk < 16; ++kk) {
            float4 a = *(const float4*)&As[kk][mr];
            float4 b = *(const float4*)&Bs[kk][nr];
            float aa[4] = {a.x, a.y, a.z, a.w};
            float bb[4] = {b.x, b.y, b.z, b.w};
#pragma unroll
            for (int i = 0; i < 4; ++i)
#pragma unroll
                for (int j = 0; j < 4; ++j) acc[i][j] += aa[i] * bb[j];
        }
    }
#pragma unroll
    for (int i = 0; i < 4; ++i) {
        int b = mr + i;
        int h = nb + nr;
        float4 o;
        o.x = acc[i][0] + b_ih[h + 0];
        o.y = acc[i][1] + b_ih[h + 1];
        o.z = acc[i][2] + b_ih[h + 2];
        o.w = acc[i][3] + b_ih[h + 3];
        *(float4*)(xp + (size_t)s * BH + (size_t)b * HID + h) = o;
    }
}

// Recurrence: 4 WGs per batch (j-chunks of 128), weights persistent in VGPRs.
// h exchanged via double-buffered global hbuf + per-batch release/acquire counter.
__global__ __launch_bounds__(512, 2) void rnn_rec4(const float* __restrict__ W_ih,
                                                   float* __restrict__ xp,
                                                   float* __restrict__ hbuf,
                                                   unsigned int* __restrict__ cnt) {
    const int b     = blockIdx.x >> 2;
    const int c     = blockIdx.x & 3;
    const int tid   = threadIdx.x;
    const int tj    = tid & 127;
    const int kq    = tid >> 7;        // 0..3
    const int j     = c * 128 + tj;    // this WG's output rows: c*128 .. c*128+127
    const int kbase = kq * 128;

    __shared__ float hlds[HID];
    __shared__ float ppart[512];

    // Persistent weights: Wh[j][kbase .. kbase+127] -> 32 float4 = 128 VGPRs
    float4 w[32];
    {
        const float* wrow = W_ih + (size_t)j * WIH_LD + IN_SZ + kbase;
#pragma unroll
        for (int i = 0; i < 32; ++i) w[i] = *(const float4*)(wrow + 4 * i);
    }

    unsigned int* cb = cnt + b;
    for (int s = 0; s < S_LEN; ++s) {
        // prefetch xp for this step (independent of h)
        float xpv = 0.f;
        if (tid < 128) xpv = xp[(size_t)s * BH + (size_t)b * HID + j];

        if (s > 0) {
            if (tid == 0) {
                while (__hip_atomic_load(cb, __ATOMIC_ACQUIRE, __HIP_MEMORY_SCOPE_AGENT)
                       < 4u * (unsigned)s)
                    __builtin_amdgcn_s_sleep(1);
            }
            __syncthreads();
        }
        // stage h_state[s] into LDS (parity s&1; parity 0 pre-zeroed for s=0)
        hlds[tid] = hbuf[(size_t)(s & 1) * BH + (size_t)b * HID + tid];
        __syncthreads();

        float acc = 0.f;
#pragma unroll
        for (int i = 0; i < 32; ++i) {
            float4 hv = *(const float4*)&hlds[kbase + 4 * i];  // wave-uniform: broadcast
            acc += w[i].x * hv.x + w[i].y * hv.y + w[i].z * hv.z + w[i].w * hv.w;
        }
        ppart[tid] = acc;
        __syncthreads();

        if (tid < 128) {
            float v = ppart[tid] + ppart[tid + 128] + ppart[tid + 256] + ppart[tid + 384] + xpv;
            v = tanhf(v);
            hbuf[(size_t)((s + 1) & 1) * BH + (size_t)b * HID + j] = v;  // h_state[s+1]
            xp[(size_t)s * BH + (size_t)b * HID + j] = v;                // hidden_seq
        }
        __threadfence();     // make writers' stores device-visible before signal
        __syncthreads();
        if (tid == 0)
            __hip_atomic_fetch_add(cb, 1u, __ATOMIC_RELEASE, __HIP_MEMORY_SCOPE_AGENT);
    }
}

// Per-batch fused: scores -> softmax -> context -> out = ctx @ W_ho^T + b_ho
__global__ __launch_bounds__(256) void attn_out(const float* __restrict__ hbuf,
                                                const float* __restrict__ W_ho,
                                                const float* __restrict__ b_ho,
                                                float* __restrict__ out) {
    const int b    = blockIdx.x;
    const int tid  = threadIdx.x;
    const int lane = tid & 63;
    const int wave = tid >> 6;   // 4 waves
    __shared__ float fh[HID];
    __shared__ float sc[S_LEN];
    __shared__ float red[4];
    __shared__ float ctx[HID];
    for (int k = tid; k < HID; k += 256)
        fh[k] = hbuf[(size_t)(S_LEN - 1) * BH + (size_t)b * HID + k];
    __syncthreads();
    for (int s = wave; s < S_LEN; s += 4) {
        const float* hr = hbuf + (size_t)s * BH + (size_t)b * HID;
        float p = 0.f;
#pragma unroll
        for (int k = lane; k < HID; k += 64) p += hr[k] * fh[k];
#pragma unroll
        for (int off = 32; off; off >>= 1) p += __shfl_down(p, off, 64);
        if (lane == 0) sc[s] = p;
    }
    __syncthreads();
    float m = -1e30f;
    for (int s2 = tid; s2 < S_LEN; s2 += 256) m = fmaxf(m, sc[s2]);
#pragma unroll
    for (int off = 32; off; off >>= 1) m = fmaxf(m, __shfl_down(m, off, 64));
    if (lane == 0) red[wave] = m;
    __syncthreads();
    m = fmaxf(fmaxf(red[0], red[1]), fmaxf(red[2], red[3]));
    float sum = 0.f;
    for (int s2 = tid; s2 < S_LEN; s2 += 256) {
        float e = expf(sc[s2] - m);
        sc[s2] = e;
        sum += e;
    }
#pragma unroll
    for (int off = 32; off; off >>= 1) sum += __shfl_down(sum, off, 64);
    __syncthreads();
    if (lane == 0) red[wave] = sum;
    __syncthreads();
    sum = red[0] + red[1] + red[2] + red[3];
    const float inv = 1.f / sum;
    float c0 = 0.f, c1 = 0.f;
    for (int s2 = 0; s2 < S_LEN; ++s2) {
        const float* hr = hbuf + (size_t)s2 * BH + (size_t)b * HID;
        float a = sc[s2] * inv;
        c0 += a * hr[tid];
        c1 += a * hr[tid + 256];
    }
    ctx[tid] = c0;
    ctx[tid + 256] = c1;
    __syncthreads();
    float oacc = b_ho[tid];
    const float* wr = W_ho + (size_t)tid * HID;
#pragma unroll 4
    for (int k = 0; k < HID; ++k) oacc += wr[k] * ctx[k];
    out[(size_t)b * OUT_SZ + tid] = oacc;
}

extern "C" void kernel_launch(void* const* d_in, const int* in_sizes, int n_in,
                              void* d_out, int out_size, void* d_ws, size_t ws_size,
                              hipStream_t stream) {
    const float* x    = (const float*)d_in[0];
    const float* W_ih = (const float*)d_in[1];
    const float* b_ih = (const float*)d_in[2];
    const float* W_ho = (const float*)d_in[3];
    const float* b_ho = (const float*)d_in[4];
    float* out = (float*)d_out;
    float* ws  = (float*)d_ws;

    float* xp          = ws;
    float* hbuf        = ws + XP_FLOATS;            // 2*BH floats
    unsigned int* cnt  = (unsigned int*)(hbuf + 2 * BH);  // BATCH uints

    // zero h_state[0] (both parities for simplicity) and the counters
    hipMemsetAsync(hbuf, 0, (size_t)(2 * BH) * sizeof(float) + BATCH * sizeof(unsigned int),
                   stream);

    xproj<<<dim3(1024, 8), dim3(256), 0, stream>>>(x, W_ih, b_ih, xp);

    {
        const float* Wp = W_ih;
        float* xpp = xp;
        float* hbp = hbuf;
        unsigned int* cp = cnt;
        void* kargs[] = {(void*)&Wp, (void*)&xpp, (void*)&hbp, (void*)&cp};
        hipLaunchCooperativeKernel((const void*)rnn_rec4, dim3(256), dim3(512),
                                   kargs, 0, stream);
    }

    attn_out<<<dim3(64), dim3(256), 0, stream>>>(xp, W_ho, b_ho, out);
}

// Round 3
// 19986.838 us; speedup vs baseline: 2.0521x; 2.0521x over previous
//
#include <hip/hip_runtime.h>
#include <cstdint>
#include <cmath>

#define S_LEN 1024
#define BATCH 64
#define IN_SZ 256
#define HID 512
#define OUT_SZ 256
#define WIH_LD 768  // W_ih leading dim = IN_SZ + HID
#define BH (BATCH * HID)            // 32768
#define XP_FLOATS (S_LEN * BH)      // 33,554,432 floats (128 MB)

// ws layout (floats):
//  [0, XP_FLOATS)                    xp / hidden_seq  [s][b][h]
//  [XP_FLOATS, +65536 float4 = 1MB)  whp4: Wh packed for coalesced persistent load

// Packed layout: for wave w (0..15), load i (0..63), lane l (0..63):
//   whp4[(w*64 + i)*64 + l] = Wh[(w&7)*64 + l][ (w>>3)*256 + 4*i .. +3 ]
// so thread (w,l)'s i-th load is whp4[w*4096 + i*64 + l] -> fully coalesced.
__global__ __launch_bounds__(256) void pack_wht(const float* __restrict__ W_ih,
                                                float4* __restrict__ whp4) {
    int o = blockIdx.x * 256 + threadIdx.x;   // 0..65535 (float4 index)
    int w = o >> 12;
    int i = (o >> 6) & 63;
    int l = o & 63;
    int j  = ((w & 7) << 6) + l;
    int k  = ((w >> 3) << 8) + (i << 2);
    const float* src = W_ih + (size_t)j * WIH_LD + IN_SZ + k;
    whp4[o] = make_float4(src[0], src[1], src[2], src[3]);
}

// xp[s][b][h] = dot(x[b][s][:], W_ih[h][0:256]) + b_ih[h]
__global__ __launch_bounds__(256) void xproj(const float* __restrict__ x,
                                             const float* __restrict__ W_ih,
                                             const float* __restrict__ b_ih,
                                             float* __restrict__ xp) {
    __shared__ float As[16][64];   // As[k][b]
    __shared__ float Bs[16][64];   // Bs[k][h]
    const int s   = blockIdx.x;
    const int nb  = blockIdx.y * 64;
    const int tid = threadIdx.x;
    const int lm  = tid >> 2;          // 0..63
    const int lk  = (tid & 3) << 2;    // 0,4,8,12
    const int mr  = (tid & 15) << 2;   // b sub-tile
    const int nr  = (tid >> 4) << 2;   // h sub-tile
    float acc[4][4] = {};
    for (int k0 = 0; k0 < IN_SZ; k0 += 16) {
        float4 av = *(const float4*)(x + ((size_t)lm * S_LEN + s) * IN_SZ + k0 + lk);
        float4 bv = *(const float4*)(W_ih + (size_t)(nb + lm) * WIH_LD + k0 + lk);
        __syncthreads();
        As[lk + 0][lm] = av.x; As[lk + 1][lm] = av.y;
        As[lk + 2][lm] = av.z; As[lk + 3][lm] = av.w;
        Bs[lk + 0][lm] = bv.x; Bs[lk + 1][lm] = bv.y;
        Bs[lk + 2][lm] = bv.z; Bs[lk + 3][lm] = bv.w;
        __syncthreads();
#pragma unroll
        for (int kk = 0; kk < 16; ++kk) {
            float4 a = *(const float4*)&As[kk][mr];
            float4 b = *(const float4*)&Bs[kk][nr];
            float aa[4] = {a.x, a.y, a.z, a.w};
            float bb[4] = {b.x, b.y, b.z, b.w};
#pragma unroll
            for (int i = 0; i < 4; ++i)
#pragma unroll
                for (int j = 0; j < 4; ++j) acc[i][j] += aa[i] * bb[j];
        }
    }
#pragma unroll
    for (int i = 0; i < 4; ++i) {
        int b = mr + i;
        int h = nb + nr;
        float4 o;
        o.x = acc[i][0] + b_ih[h + 0];
        o.y = acc[i][1] + b_ih[h + 1];
        o.z = acc[i][2] + b_ih[h + 2];
        o.w = acc[i][3] + b_ih[h + 3];
        *(float4*)(xp + (size_t)s * BH + (size_t)b * HID + h) = o;
    }
}

// Recurrence: one WG (1024 thr) per batch. Wh persistent in VGPRs:
// thread (j = tid&511, kh = tid>>9) holds Wh[j][kh*256 .. +255] = 64 float4.
// h double-buffered in LDS (broadcast reads), split-K=2 reduce via LDS.
__global__ __launch_bounds__(1024, 4) void rnn_pw(const float4* __restrict__ whp4,
                                                  float* __restrict__ xp) {
    const int b    = blockIdx.x;
    const int tid  = threadIdx.x;
    const int wv   = tid >> 6;       // wave 0..15
    const int lane = tid & 63;
    const int j    = tid & 511;
    const int kh   = tid >> 9;       // 0 or 1
    const int kbase = kh << 8;       // 0 or 256

    __shared__ float h[2][HID];
    __shared__ float pp[512];

    // persistent weights, coalesced load from packed layout
    float4 w[64];
    {
        const float4* base = whp4 + ((size_t)wv << 12) + lane;
#pragma unroll
        for (int i = 0; i < 64; ++i) w[i] = base[i << 6];
    }

    if (tid < HID) h[0][tid] = 0.f;
    __syncthreads();

    float* col = xp + (size_t)b * HID + j;
    for (int s = 0; s < S_LEN; ++s) {
        float xpv = 0.f;
        if (kh == 0) xpv = col[(size_t)s * BH];   // independent prefetch

        const float* hc = &h[s & 1][kbase];
        float acc = 0.f;
#pragma unroll
        for (int i = 0; i < 64; ++i) {
            float4 hv = *(const float4*)(hc + (i << 2));   // wave-uniform -> broadcast
            acc += w[i].x * hv.x + w[i].y * hv.y + w[i].z * hv.z + w[i].w * hv.w;
        }
        if (kh == 1) pp[j] = acc;
        __syncthreads();                 // pp visible
        if (kh == 0) {
            float v = tanhf(acc + pp[j] + xpv);
            h[(s + 1) & 1][j] = v;       // next-step state (other buffer)
            col[(size_t)s * BH] = v;     // hidden_seq
        }
        __syncthreads();                 // new h visible before next iter
    }
}

// Per-batch fused: scores -> softmax -> context -> out = ctx @ W_ho^T + b_ho
__global__ __launch_bounds__(256) void attn_out(const float* __restrict__ hbuf,
                                                const float* __restrict__ W_ho,
                                                const float* __restrict__ b_ho,
                                                float* __restrict__ out) {
    const int b    = blockIdx.x;
    const int tid  = threadIdx.x;
    const int lane = tid & 63;
    const int wave = tid >> 6;   // 4 waves
    __shared__ float fh[HID];
    __shared__ float sc[S_LEN];
    __shared__ float red[4];
    __shared__ float ctx[HID];
    for (int k = tid; k < HID; k += 256)
        fh[k] = hbuf[(size_t)(S_LEN - 1) * BH + (size_t)b * HID + k];
    __syncthreads();
    for (int s = wave; s < S_LEN; s += 4) {
        const float* hr = hbuf + (size_t)s * BH + (size_t)b * HID;
        float p = 0.f;
#pragma unroll
        for (int k = lane; k < HID; k += 64) p += hr[k] * fh[k];
#pragma unroll
        for (int off = 32; off; off >>= 1) p += __shfl_down(p, off, 64);
        if (lane == 0) sc[s] = p;
    }
    __syncthreads();
    float m = -1e30f;
    for (int s2 = tid; s2 < S_LEN; s2 += 256) m = fmaxf(m, sc[s2]);
#pragma unroll
    for (int off = 32; off; off >>= 1) m = fmaxf(m, __shfl_down(m, off, 64));
    if (lane == 0) red[wave] = m;
    __syncthreads();
    m = fmaxf(fmaxf(red[0], red[1]), fmaxf(red[2], red[3]));
    float sum = 0.f;
    for (int s2 = tid; s2 < S_LEN; s2 += 256) {
        float e = expf(sc[s2] - m);
        sc[s2] = e;
        sum += e;
    }
#pragma unroll
    for (int off = 32; off; off >>= 1) sum += __shfl_down(sum, off, 64);
    __syncthreads();
    if (lane == 0) red[wave] = sum;
    __syncthreads();
    sum = red[0] + red[1] + red[2] + red[3];
    const float inv = 1.f / sum;
    float c0 = 0.f, c1 = 0.f;
    for (int s2 = 0; s2 < S_LEN; ++s2) {
        const float* hr = hbuf + (size_t)s2 * BH + (size_t)b * HID;
        float a = sc[s2] * inv;
        c0 += a * hr[tid];
        c1 += a * hr[tid + 256];
    }
    ctx[tid] = c0;
    ctx[tid + 256] = c1;
    __syncthreads();
    float oacc = b_ho[tid];
    const float* wr = W_ho + (size_t)tid * HID;
#pragma unroll 4
    for (int k = 0; k < HID; ++k) oacc += wr[k] * ctx[k];
    out[(size_t)b * OUT_SZ + tid] = oacc;
}

extern "C" void kernel_launch(void* const* d_in, const int* in_sizes, int n_in,
                              void* d_out, int out_size, void* d_ws, size_t ws_size,
                              hipStream_t stream) {
    const float* x    = (const float*)d_in[0];
    const float* W_ih = (const float*)d_in[1];
    const float* b_ih = (const float*)d_in[2];
    const float* W_ho = (const float*)d_in[3];
    const float* b_ho = (const float*)d_in[4];
    float* out = (float*)d_out;
    float* ws  = (float*)d_ws;

    float*  xp   = ws;
    float4* whp4 = (float4*)(ws + XP_FLOATS);   // 65536 float4 (1 MB)

    pack_wht<<<dim3(256), dim3(256), 0, stream>>>(W_ih, whp4);
    xproj<<<dim3(1024, 8), dim3(256), 0, stream>>>(x, W_ih, b_ih, xp);
    rnn_pw<<<dim3(64), dim3(1024), 0, stream>>>(whp4, xp);
    attn_out<<<dim3(64), dim3(256), 0, stream>>>(xp, W_ho, b_ho, out);
}

// Round 4
// 2218.394 us; speedup vs baseline: 18.4886x; 9.0096x over previous
//
#include <hip/hip_runtime.h>
#include <cstdint>
#include <cmath>

#define S_LEN 1024
#define BATCH 64
#define IN_SZ 256
#define HID 512
#define OUT_SZ 256
#define WIH_LD 768  // W_ih leading dim = IN_SZ + HID
#define BH (BATCH * HID)            // 32768
#define XP_FLOATS (S_LEN * BH)      // 33,554,432 floats (128 MB)

// Weight pair-index space: p = k/2, p in [0,256). Per output row j (0..511):
//   p in [0,176)    -> VGPR-resident   (wregbuf[p*512 + j])
//   p in [176,200)  -> LDS-resident    (wldsbuf[(p-176)*512 + j])
//   p in [200,256)  -> streamed/step   (wstr uint4: group g=(p-200)/4, word (g*512+j)*4+((p-200)&3))
#define P_REG 176
#define P_LDS 24
#define P_STR_G 14   // 14 groups x 4 pairs = 56 pairs

// ws layout (32-bit words after xp):
//  [0, XP_FLOATS)                 xp / hidden_seq  [s][b][h]  (fp32)
//  +0      .. +28671              wstr   (7168 uint4)
//  +28672  .. +118783             wregbuf (176*512 uint)
//  +118784 .. +131071             wldsbuf (24*512 uint)

typedef _Float16 h2v __attribute__((ext_vector_type(2)));

__device__ __forceinline__ float dot2p(unsigned int a, unsigned int b, float c) {
#if __has_builtin(__builtin_amdgcn_fdot2)
    return __builtin_amdgcn_fdot2(__builtin_bit_cast(h2v, a),
                                  __builtin_bit_cast(h2v, b), c, false);
#else
    h2v av = __builtin_bit_cast(h2v, a);
    h2v bv = __builtin_bit_cast(h2v, b);
    return c + (float)av.x * (float)bv.x + (float)av.y * (float)bv.y;
#endif
}

__global__ __launch_bounds__(256) void pack_w(const float* __restrict__ W_ih,
                                              unsigned int* __restrict__ wstr,
                                              unsigned int* __restrict__ wregbuf,
                                              unsigned int* __restrict__ wldsbuf) {
    int idx = blockIdx.x * 256 + threadIdx.x;   // 0..131071
    int p = idx & 255;
    int j = idx >> 8;
    const float* src = W_ih + (size_t)j * WIH_LD + IN_SZ + 2 * p;
    unsigned short lo = __builtin_bit_cast(unsigned short, (_Float16)src[0]);
    unsigned short hi = __builtin_bit_cast(unsigned short, (_Float16)src[1]);
    unsigned int u = (unsigned int)lo | ((unsigned int)hi << 16);
    if (p < P_REG) {
        wregbuf[p * 512 + j] = u;
    } else if (p < P_REG + P_LDS) {
        wldsbuf[(p - P_REG) * 512 + j] = u;
    } else {
        int q = p - (P_REG + P_LDS);
        wstr[((q >> 2) * 512 + j) * 4 + (q & 3)] = u;
    }
}

// xp[s][b][h] = dot(x[b][s][:], W_ih[h][0:256]) + b_ih[h]
__global__ __launch_bounds__(256) void xproj(const float* __restrict__ x,
                                             const float* __restrict__ W_ih,
                                             const float* __restrict__ b_ih,
                                             float* __restrict__ xp) {
    __shared__ float As[16][64];   // As[k][b]
    __shared__ float Bs[16][64];   // Bs[k][h]
    const int s   = blockIdx.x;
    const int nb  = blockIdx.y * 64;
    const int tid = threadIdx.x;
    const int lm  = tid >> 2;          // 0..63
    const int lk  = (tid & 3) << 2;    // 0,4,8,12
    const int mr  = (tid & 15) << 2;   // b sub-tile
    const int nr  = (tid >> 4) << 2;   // h sub-tile
    float acc[4][4] = {};
    for (int k0 = 0; k0 < IN_SZ; k0 += 16) {
        float4 av = *(const float4*)(x + ((size_t)lm * S_LEN + s) * IN_SZ + k0 + lk);
        float4 bv = *(const float4*)(W_ih + (size_t)(nb + lm) * WIH_LD + k0 + lk);
        __syncthreads();
        As[lk + 0][lm] = av.x; As[lk + 1][lm] = av.y;
        As[lk + 2][lm] = av.z; As[lk + 3][lm] = av.w;
        Bs[lk + 0][lm] = bv.x; Bs[lk + 1][lm] = bv.y;
        Bs[lk + 2][lm] = bv.z; Bs[lk + 3][lm] = bv.w;
        __syncthreads();
#pragma unroll
        for (int kk = 0; kk < 16; ++kk) {
            float4 a = *(const float4*)&As[kk][mr];
            float4 b = *(const float4*)&Bs[kk][nr];
            float aa[4] = {a.x, a.y, a.z, a.w};
            float bb[4] = {b.x, b.y, b.z, b.w};
#pragma unroll
            for (int i = 0; i < 4; ++i)
#pragma unroll
                for (int jj = 0; jj < 4; ++jj) acc[i][jj] += aa[i] * bb[jj];
        }
    }
#pragma unroll
    for (int i = 0; i < 4; ++i) {
        int b = mr + i;
        int h = nb + nr;
        float4 o;
        o.x = acc[i][0] + b_ih[h + 0];
        o.y = acc[i][1] + b_ih[h + 1];
        o.z = acc[i][2] + b_ih[h + 2];
        o.w = acc[i][3] + b_ih[h + 3];
        *(float4*)(xp + (size_t)s * BH + (size_t)b * HID + h) = o;
    }
}

// Recurrence: one WG (512 thr, 8 waves, 2/SIMD -> VGPR cap 256) per batch.
// Thread j owns output row j. Weights: 176 pairs in VGPRs + 24 pairs in LDS
// + 56 pairs streamed from L2 per step. h state: packed f16 in LDS, dbl-buffered.
__global__ __launch_bounds__(512, 2) void rnn_f16(const unsigned int* __restrict__ wregbuf,
                                                  const unsigned int* __restrict__ wldsbuf,
                                                  const uint4* __restrict__ wstr,
                                                  float* __restrict__ xp) {
    const int b = blockIdx.x;
    const int j = threadIdx.x;

    __shared__ unsigned int wlds[P_LDS * 512];      // 48 KB, [p][j]
    __shared__ unsigned short h2u[2][512];          // 2 KB, packed f16 state

    // persistent weights (coalesced: consecutive j -> consecutive addresses)
    unsigned int wreg[P_REG];
#pragma unroll
    for (int p = 0; p < P_REG; ++p) wreg[p] = wregbuf[p * 512 + j];

    for (int g = j; g < P_LDS * 512; g += 512) wlds[g] = wldsbuf[g];
    h2u[0][j] = 0;   // f16 +0.0
    __syncthreads();

    float* col = xp + (size_t)b * HID + j;
    for (int s = 0; s < S_LEN; ++s) {
        const unsigned int* hq = (const unsigned int*)h2u[s & 1];  // 256 pairs
        float acc = col[(size_t)s * BH];             // xp prefetch (independent)

        uint4 sw[P_STR_G];
#pragma unroll
        for (int g = 0; g < P_STR_G; ++g) sw[g] = wstr[(size_t)g * 512 + j];

#pragma unroll
        for (int p = 0; p < P_REG; ++p) acc = dot2p(wreg[p], hq[p], acc);
#pragma unroll
        for (int p = 0; p < P_LDS; ++p) acc = dot2p(wlds[p * 512 + j], hq[P_REG + p], acc);
#pragma unroll
        for (int g = 0; g < P_STR_G; ++g) {
            int pb = P_REG + P_LDS + 4 * g;
            acc = dot2p(sw[g].x, hq[pb + 0], acc);
            acc = dot2p(sw[g].y, hq[pb + 1], acc);
            acc = dot2p(sw[g].z, hq[pb + 2], acc);
            acc = dot2p(sw[g].w, hq[pb + 3], acc);
        }

        float v = tanhf(acc);
        col[(size_t)s * BH] = v;                                   // hidden_seq (fp32)
        h2u[(s + 1) & 1][j] = __builtin_bit_cast(unsigned short, (_Float16)v);
        __syncthreads();   // next-step reads of h2u[(s+1)&1] safe; cur buffer free
    }
}

// Per-batch fused: scores -> softmax -> context -> out = ctx @ W_ho^T + b_ho
__global__ __launch_bounds__(256) void attn_out(const float* __restrict__ hbuf,
                                                const float* __restrict__ W_ho,
                                                const float* __restrict__ b_ho,
                                                float* __restrict__ out) {
    const int b    = blockIdx.x;
    const int tid  = threadIdx.x;
    const int lane = tid & 63;
    const int wave = tid >> 6;   // 4 waves
    __shared__ float fh[HID];
    __shared__ float sc[S_LEN];
    __shared__ float red[4];
    __shared__ float ctx[HID];
    for (int k = tid; k < HID; k += 256)
        fh[k] = hbuf[(size_t)(S_LEN - 1) * BH + (size_t)b * HID + k];
    __syncthreads();
    for (int s = wave; s < S_LEN; s += 4) {
        const float* hr = hbuf + (size_t)s * BH + (size_t)b * HID;
        float p = 0.f;
#pragma unroll
        for (int k = lane; k < HID; k += 64) p += hr[k] * fh[k];
#pragma unroll
        for (int off = 32; off; off >>= 1) p += __shfl_down(p, off, 64);
        if (lane == 0) sc[s] = p;
    }
    __syncthreads();
    float m = -1e30f;
    for (int s2 = tid; s2 < S_LEN; s2 += 256) m = fmaxf(m, sc[s2]);
#pragma unroll
    for (int off = 32; off; off >>= 1) m = fmaxf(m, __shfl_down(m, off, 64));
    if (lane == 0) red[wave] = m;
    __syncthreads();
    m = fmaxf(fmaxf(red[0], red[1]), fmaxf(red[2], red[3]));
    float sum = 0.f;
    for (int s2 = tid; s2 < S_LEN; s2 += 256) {
        float e = expf(sc[s2] - m);
        sc[s2] = e;
        sum += e;
    }
#pragma unroll
    for (int off = 32; off; off >>= 1) sum += __shfl_down(sum, off, 64);
    __syncthreads();
    if (lane == 0) red[wave] = sum;
    __syncthreads();
    sum = red[0] + red[1] + red[2] + red[3];
    const float inv = 1.f / sum;
    float c0 = 0.f, c1 = 0.f;
    for (int s2 = 0; s2 < S_LEN; ++s2) {
        const float* hr = hbuf + (size_t)s2 * BH + (size_t)b * HID;
        float a = sc[s2] * inv;
        c0 += a * hr[tid];
        c1 += a * hr[tid + 256];
    }
    ctx[tid] = c0;
    ctx[tid + 256] = c1;
    __syncthreads();
    float oacc = b_ho[tid];
    const float* wr = W_ho + (size_t)tid * HID;
#pragma unroll 4
    for (int k = 0; k < HID; ++k) oacc += wr[k] * ctx[k];
    out[(size_t)b * OUT_SZ + tid] = oacc;
}

extern "C" void kernel_launch(void* const* d_in, const int* in_sizes, int n_in,
                              void* d_out, int out_size, void* d_ws, size_t ws_size,
                              hipStream_t stream) {
    const float* x    = (const float*)d_in[0];
    const float* W_ih = (const float*)d_in[1];
    const float* b_ih = (const float*)d_in[2];
    const float* W_ho = (const float*)d_in[3];
    const float* b_ho = (const float*)d_in[4];
    float* out = (float*)d_out;
    float* ws  = (float*)d_ws;

    float* xp = ws;
    unsigned int* wbase   = (unsigned int*)(ws + XP_FLOATS);
    unsigned int* wstr    = wbase;                         // 28672 words (uint4-aligned)
    unsigned int* wregbuf = wbase + 28672;                 // 90112 words
    unsigned int* wldsbuf = wbase + 28672 + P_REG * 512;   // 12288 words

    pack_w<<<dim3(512), dim3(256), 0, stream>>>(W_ih, wstr, wregbuf, wldsbuf);
    xproj<<<dim3(1024, 8), dim3(256), 0, stream>>>(x, W_ih, b_ih, xp);
    rnn_f16<<<dim3(64), dim3(512), 0, stream>>>(wregbuf, wldsbuf, (const uint4*)wstr, xp);
    attn_out<<<dim3(64), dim3(256), 0, stream>>>(xp, W_ho, b_ho, out);
}